// Round 1
// baseline (614.856 us; speedup 1.0000x reference)
//
#include <hip/hip_runtime.h>
#include <math.h>

#define NNODES   50000
#define NFEAT    512
#define NCLASS   256
#define NEG_SLOPE 0.2f

// ---------------------------------------------------------------------------
// GEMM: h = x @ W   (M x 512) @ (512 x 256), fp32
// 64x64 tile, BK=16, 256 threads, 4x4 micro-tile per thread.
// ---------------------------------------------------------------------------
__global__ __launch_bounds__(256) void gemm_kernel(const float* __restrict__ A,
                                                   const float* __restrict__ B,
                                                   float* __restrict__ C, int M) {
    __shared__ float As[16][64];   // [k][m]
    __shared__ float Bs[16][64];   // [k][n]
    const int tid = threadIdx.x;
    const int rowbase = blockIdx.x * 64;
    const int nbase   = blockIdx.y * 64;
    const int tm = tid >> 4;        // 0..15 -> 4 rows each
    const int tn = tid & 15;        // 0..15 -> 4 cols each

    float acc[4][4] = {};

    // A staging map: thread loads float4 along K. ar in 0..63, ak4 in {0,4,8,12}
    const int ar  = tid >> 2;
    const int ak4 = (tid & 3) << 2;
    // B staging map: bk in 0..15, bn4 = 4*(0..15)
    const int bk  = tid >> 4;
    const int bn4 = (tid & 15) << 2;

    const int arow = rowbase + ar;

    for (int k0 = 0; k0 < NFEAT; k0 += 16) {
        float4 av = make_float4(0.f, 0.f, 0.f, 0.f);
        if (arow < M)
            av = *(const float4*)&A[(size_t)arow * NFEAT + k0 + ak4];
        As[ak4 + 0][ar] = av.x;
        As[ak4 + 1][ar] = av.y;
        As[ak4 + 2][ar] = av.z;
        As[ak4 + 3][ar] = av.w;

        const float4 bv = *(const float4*)&B[(size_t)(k0 + bk) * NCLASS + nbase + bn4];
        *(float4*)&Bs[bk][bn4] = bv;

        __syncthreads();

#pragma unroll
        for (int kk = 0; kk < 16; ++kk) {
            const float4 a4 = *(const float4*)&As[kk][tm << 2];
            const float4 b4 = *(const float4*)&Bs[kk][tn << 2];
            const float a_[4] = {a4.x, a4.y, a4.z, a4.w};
            const float b_[4] = {b4.x, b4.y, b4.z, b4.w};
#pragma unroll
            for (int i = 0; i < 4; ++i)
#pragma unroll
                for (int j = 0; j < 4; ++j)
                    acc[i][j] += a_[i] * b_[j];
        }
        __syncthreads();
    }

#pragma unroll
    for (int i = 0; i < 4; ++i) {
        const int row = rowbase + (tm << 2) + i;
        if (row < M) {
            float4 o = make_float4(acc[i][0], acc[i][1], acc[i][2], acc[i][3]);
            *(float4*)&C[(size_t)row * NCLASS + nbase + (tn << 2)] = o;
        }
    }
}

// ---------------------------------------------------------------------------
// s_row[i] = h[i,:] . a[0:256],  s_col[i] = h[i,:] . a[256:512]
// one wave per row, float4 per lane (64*4 = 256)
// ---------------------------------------------------------------------------
__global__ __launch_bounds__(256) void compute_s_kernel(const float* __restrict__ h,
                                                        const float* __restrict__ a,
                                                        float* __restrict__ s_row,
                                                        float* __restrict__ s_col, int n) {
    const int wave = (int)((blockIdx.x * (size_t)blockDim.x + threadIdx.x) >> 6);
    const int lane = threadIdx.x & 63;
    if (wave >= n) return;
    const float4 hv = *(const float4*)&h[(size_t)wave * NCLASS + (lane << 2)];
    const float4 a1 = *(const float4*)&a[lane << 2];
    const float4 a2 = *(const float4*)&a[NCLASS + (lane << 2)];
    float d1 = hv.x * a1.x + hv.y * a1.y + hv.z * a1.z + hv.w * a1.w;
    float d2 = hv.x * a2.x + hv.y * a2.y + hv.z * a2.z + hv.w * a2.w;
#pragma unroll
    for (int off = 32; off > 0; off >>= 1) {
        d1 += __shfl_xor(d1, off);
        d2 += __shfl_xor(d2, off);
    }
    if (lane == 0) {
        s_row[wave] = d1;
        s_col[wave] = d2;
    }
}

// ---------------------------------------------------------------------------
// CSR build: histogram -> scan -> scatter
// ---------------------------------------------------------------------------
__global__ __launch_bounds__(256) void hist_kernel(const int* __restrict__ row,
                                                   int* __restrict__ deg, int e) {
    const int i = blockIdx.x * 256 + threadIdx.x;
    if (i < e) atomicAdd(&deg[row[i]], 1);
}

__global__ __launch_bounds__(1024) void scan_kernel(const int* __restrict__ deg,
                                                    int* __restrict__ rowstart, int n) {
    __shared__ int buf[1024];
    __shared__ int s_running;
    if (threadIdx.x == 0) s_running = 0;
    __syncthreads();
    for (int base = 0; base < n; base += 1024) {
        const int i = base + (int)threadIdx.x;
        int v = (i < n) ? deg[i] : 0;
        buf[threadIdx.x] = v;
        __syncthreads();
        for (int off = 1; off < 1024; off <<= 1) {
            int t = (threadIdx.x >= (unsigned)off) ? buf[threadIdx.x - off] : 0;
            __syncthreads();
            buf[threadIdx.x] += t;
            __syncthreads();
        }
        const int incl = buf[threadIdx.x];
        const int run = s_running;
        if (i < n) rowstart[i + 1] = run + incl;
        __syncthreads();
        if (threadIdx.x == 1023) s_running = run + incl;
        __syncthreads();
    }
    if (threadIdx.x == 0) rowstart[0] = 0;
}

__global__ __launch_bounds__(256) void scatter_kernel(const int* __restrict__ row,
                                                      const int* __restrict__ col,
                                                      const int* __restrict__ rowstart,
                                                      int* __restrict__ cursor,
                                                      int* __restrict__ sorted_col, int e) {
    const int i = blockIdx.x * 256 + threadIdx.x;
    if (i >= e) return;
    const int r = row[i];
    const int pos = atomicAdd(&cursor[r], 1);
    sorted_col[rowstart[r] + pos] = col[i];
}

// ---------------------------------------------------------------------------
// Aggregation + elu + log_softmax. One wave per row; lane holds 4 features.
// ---------------------------------------------------------------------------
__global__ __launch_bounds__(256) void aggregate_kernel(const float* __restrict__ h,
                                                        const float* __restrict__ s_row,
                                                        const float* __restrict__ s_col,
                                                        const int* __restrict__ rowstart,
                                                        const int* __restrict__ sorted_col,
                                                        float* __restrict__ out, int n) {
    const int wave = (int)((blockIdx.x * (size_t)blockDim.x + threadIdx.x) >> 6);
    const int lane = threadIdx.x & 63;
    if (wave >= n) return;
    const int r = wave;
    const int jb = rowstart[r];
    const int je = rowstart[r + 1];
    const float sr = s_row[r];

    float4 acc = make_float4(0.f, 0.f, 0.f, 0.f);
    float rowsum = 0.f;

    for (int j = jb; j < je; ++j) {
        const int c = sorted_col[j];
        const float logit = sr + s_col[c];
        const float lr = logit > 0.f ? logit : NEG_SLOPE * logit;
        const float e = __expf(-lr);
        rowsum += e;
        const float4 hv = *(const float4*)&h[(size_t)c * NCLASS + (lane << 2)];
        acc.x += e * hv.x;
        acc.y += e * hv.y;
        acc.z += e * hv.z;
        acc.w += e * hv.w;
    }

    const float inv = 1.f / rowsum;
    float v[4] = {acc.x * inv, acc.y * inv, acc.z * inv, acc.w * inv};
#pragma unroll
    for (int i = 0; i < 4; ++i)
        v[i] = v[i] > 0.f ? v[i] : __expf(v[i]) - 1.f;

    // log_softmax over the wave's 256 values
    float m = fmaxf(fmaxf(v[0], v[1]), fmaxf(v[2], v[3]));
#pragma unroll
    for (int off = 32; off > 0; off >>= 1) m = fmaxf(m, __shfl_xor(m, off));
    float s = 0.f;
#pragma unroll
    for (int i = 0; i < 4; ++i) s += __expf(v[i] - m);
#pragma unroll
    for (int off = 32; off > 0; off >>= 1) s += __shfl_xor(s, off);
    const float lse = m + __logf(s);

    float4 o = make_float4(v[0] - lse, v[1] - lse, v[2] - lse, v[3] - lse);
    *(float4*)&out[(size_t)r * NCLASS + (lane << 2)] = o;
}

// ---------------------------------------------------------------------------
extern "C" void kernel_launch(void* const* d_in, const int* in_sizes, int n_in,
                              void* d_out, int out_size, void* d_ws, size_t ws_size,
                              hipStream_t stream) {
    const float* x  = (const float*)d_in[0];   // [N, 512]
    const float* W  = (const float*)d_in[1];   // [512, 256]
    const float* a  = (const float*)d_in[2];   // [512]
    const int* edge = (const int*)d_in[3];     // [2, E]
    float* out = (float*)d_out;

    const int M = in_sizes[0] / NFEAT;         // 50000
    const int E = in_sizes[3] / 2;             // 850000
    const int* row = edge;
    const int* col = edge + E;

    // workspace carve-up (256B aligned)
    char* ws = (char*)d_ws;
    size_t off = 0;
    auto carve = [&](size_t bytes) -> char* {
        char* p = ws + off;
        off = (off + bytes + 255) & ~(size_t)255;
        return p;
    };
    float* h        = (float*)carve((size_t)M * NCLASS * sizeof(float));
    float* s_row    = (float*)carve((size_t)M * sizeof(float));
    float* s_col    = (float*)carve((size_t)M * sizeof(float));
    int*   deg      = (int*)carve((size_t)2 * M * sizeof(int));  // deg + cursor contiguous
    int*   cursor   = deg + M;
    int*   rowstart = (int*)carve((size_t)(M + 1) * sizeof(int));
    int*   sorted_col = (int*)carve((size_t)E * sizeof(int));

    hipMemsetAsync(deg, 0, (size_t)2 * M * sizeof(int), stream);

    dim3 ggrid((M + 63) / 64, NCLASS / 64);
    gemm_kernel<<<ggrid, 256, 0, stream>>>(x, W, h, M);

    compute_s_kernel<<<(M + 3) / 4, 256, 0, stream>>>(h, a, s_row, s_col, M);

    hist_kernel<<<(E + 255) / 256, 256, 0, stream>>>(row, deg, E);
    scan_kernel<<<1, 1024, 0, stream>>>(deg, rowstart, M);
    scatter_kernel<<<(E + 255) / 256, 256, 0, stream>>>(row, col, rowstart, cursor, sorted_col, E);

    aggregate_kernel<<<(M + 3) / 4, 256, 0, stream>>>(h, s_row, s_col, rowstart, sorted_col, out, M);
}

// Round 2
// 372.778 us; speedup vs baseline: 1.6494x; 1.6494x over previous
//
#include <hip/hip_runtime.h>
#include <math.h>

#define NNODES   50000
#define NFEAT    512
#define NCLASS   256
#define NEG_SLOPE 0.2f
#define MPAD     50048   // 391 * 128

typedef __attribute__((ext_vector_type(8))) short short8;
typedef __attribute__((ext_vector_type(4))) float floatx4;

__device__ __forceinline__ unsigned short f2bf(float f) {
    unsigned u = __builtin_bit_cast(unsigned, f);
    u += 0x7fffu + ((u >> 16) & 1u);          // RNE
    return (unsigned short)(u >> 16);
}
__device__ __forceinline__ float bf2f(unsigned short s) {
    unsigned u = ((unsigned)s) << 16;
    return __builtin_bit_cast(float, u);
}

// ---------------------------------------------------------------------------
// fp32 -> bf16 conversion of x. Each thread: 8 floats -> 8 bf16 (16B store).
// ---------------------------------------------------------------------------
__global__ __launch_bounds__(256) void cvt_x_kernel(const float* __restrict__ x,
                                                    unsigned short* __restrict__ xb, int n8) {
    const int i = blockIdx.x * 256 + threadIdx.x;
    if (i >= n8) return;
    const float4* p = (const float4*)(x + (size_t)i * 8);
    const float4 v0 = p[0];
    const float4 v1 = p[1];
    uint4 o;
    o.x = (unsigned)f2bf(v0.x) | ((unsigned)f2bf(v0.y) << 16);
    o.y = (unsigned)f2bf(v0.z) | ((unsigned)f2bf(v0.w) << 16);
    o.z = (unsigned)f2bf(v1.x) | ((unsigned)f2bf(v1.y) << 16);
    o.w = (unsigned)f2bf(v1.z) | ((unsigned)f2bf(v1.w) << 16);
    *(uint4*)(xb + (size_t)i * 8) = o;
}

// W [512][256] fp32 -> Wt [256][512] bf16 (transposed)
__global__ __launch_bounds__(256) void cvt_wt_kernel(const float* __restrict__ W,
                                                     unsigned short* __restrict__ Wt) {
    const int tid = blockIdx.x * 256 + threadIdx.x;   // 131072 threads
    const int n = tid >> 9;
    const int k = tid & 511;
    Wt[tid] = f2bf(W[(size_t)k * NCLASS + n]);
}

// ---------------------------------------------------------------------------
// MFMA GEMM: hb = bf16( xb[MPAD,512] @ Wt^T )  -> [M,256] bf16
// 128x128 block tile, 4 waves (2x2 of 64x64), BK=32, global_load_lds(16B).
// ---------------------------------------------------------------------------
__global__ __launch_bounds__(256) void gemm_mfma_kernel(const unsigned short* __restrict__ xb,
                                                        const unsigned short* __restrict__ Wt,
                                                        unsigned short* __restrict__ hb, int M) {
    __shared__ short As[128 * 32];   // [row][k], 64B rows
    __shared__ short Bs[128 * 32];   // [n][k],   64B rows

    const int tid  = threadIdx.x;
    const int w    = tid >> 6;
    const int lane = tid & 63;
    const int rowbase = blockIdx.x * 128;
    const int nbase   = blockIdx.y * 128;

    const int wm = w & 1;   // wave's 64-row half
    const int wn = w >> 1;  // wave's 64-col half

    // staging: wave w covers segs {2w, 2w+1}; each seg = 16 rows x 32 k (1024B)
    const int srow = (lane >> 2);        // 0..15 within seg
    const int skq  = (lane & 3) << 3;    // k offset 0,8,16,24

    // fragment LDS offsets (in shorts)
    const int fm = lane & 15;
    const int fq = lane >> 4;

    floatx4 acc[4][4];
#pragma unroll
    for (int i = 0; i < 4; ++i)
#pragma unroll
        for (int j = 0; j < 4; ++j)
            acc[i][j] = (floatx4){0.f, 0.f, 0.f, 0.f};

    for (int k0 = 0; k0 < NFEAT; k0 += 32) {
#pragma unroll
        for (int t = 0; t < 2; ++t) {
            const int seg = w * 2 + t;
            const int r = seg * 16 + srow;
            __builtin_amdgcn_global_load_lds(
                (const __attribute__((address_space(1))) void*)(xb + (size_t)(rowbase + r) * NFEAT + k0 + skq),
                (__attribute__((address_space(3))) void*)(As + seg * 512), 16, 0, 0);
            __builtin_amdgcn_global_load_lds(
                (const __attribute__((address_space(1))) void*)(Wt + (size_t)(nbase + r) * NFEAT + k0 + skq),
                (__attribute__((address_space(3))) void*)(Bs + seg * 512), 16, 0, 0);
        }
        __syncthreads();

        short8 af[4], bf[4];
#pragma unroll
        for (int mt = 0; mt < 4; ++mt)
            af[mt] = *(const short8*)&As[(wm * 64 + mt * 16 + fm) * 32 + fq * 8];
#pragma unroll
        for (int nt = 0; nt < 4; ++nt)
            bf[nt] = *(const short8*)&Bs[(wn * 64 + nt * 16 + fm) * 32 + fq * 8];

#pragma unroll
        for (int mt = 0; mt < 4; ++mt)
#pragma unroll
            for (int nt = 0; nt < 4; ++nt)
                acc[mt][nt] = __builtin_amdgcn_mfma_f32_16x16x32_bf16(af[mt], bf[nt], acc[mt][nt], 0, 0, 0);

        __syncthreads();
    }

    // C/D layout: col = lane&15, row = (lane>>4)*4 + r
#pragma unroll
    for (int mt = 0; mt < 4; ++mt) {
#pragma unroll
        for (int nt = 0; nt < 4; ++nt) {
            const int gcol = nbase + wn * 64 + nt * 16 + fm;
#pragma unroll
            for (int r = 0; r < 4; ++r) {
                const int grow = rowbase + wm * 64 + mt * 16 + fq * 4 + r;
                if (grow < M)
                    hb[(size_t)grow * NCLASS + gcol] = f2bf(acc[mt][nt][r]);
            }
        }
    }
}

// ---------------------------------------------------------------------------
// s_row[i] = h[i,:].a[0:256], s_col[i] = h[i,:].a[256:512]; one wave per row
// ---------------------------------------------------------------------------
__global__ __launch_bounds__(256) void compute_s_kernel(const unsigned short* __restrict__ hb,
                                                        const float* __restrict__ a,
                                                        float* __restrict__ s_row,
                                                        float* __restrict__ s_col, int n) {
    const int wave = (int)((blockIdx.x * (size_t)blockDim.x + threadIdx.x) >> 6);
    const int lane = threadIdx.x & 63;
    if (wave >= n) return;
    const ushort4 hv = *(const ushort4*)&hb[(size_t)wave * NCLASS + (lane << 2)];
    const float4 a1 = *(const float4*)&a[lane << 2];
    const float4 a2 = *(const float4*)&a[NCLASS + (lane << 2)];
    const float h0 = bf2f(hv.x), h1 = bf2f(hv.y), h2 = bf2f(hv.z), h3 = bf2f(hv.w);
    float d1 = h0 * a1.x + h1 * a1.y + h2 * a1.z + h3 * a1.w;
    float d2 = h0 * a2.x + h1 * a2.y + h2 * a2.z + h3 * a2.w;
#pragma unroll
    for (int off = 32; off > 0; off >>= 1) {
        d1 += __shfl_xor(d1, off);
        d2 += __shfl_xor(d2, off);
    }
    if (lane == 0) {
        s_row[wave] = d1;
        s_col[wave] = d2;
    }
}

// ---------------------------------------------------------------------------
// CSR build: histogram -> two-level scan -> scatter
// ---------------------------------------------------------------------------
__global__ __launch_bounds__(256) void hist_kernel(const int* __restrict__ row,
                                                   int* __restrict__ deg, int e) {
    const int i = blockIdx.x * 256 + threadIdx.x;
    if (i < e) atomicAdd(&deg[row[i]], 1);
}

// per-block inclusive scan of 256 elements; writes incl to tmp, total to blocksum
__global__ __launch_bounds__(256) void scan1_kernel(const int* __restrict__ deg,
                                                    int* __restrict__ tmp,
                                                    int* __restrict__ blocksum, int n) {
    __shared__ int buf[256];
    const int i = blockIdx.x * 256 + threadIdx.x;
    const int t = threadIdx.x;
    buf[t] = (i < n) ? deg[i] : 0;
    __syncthreads();
#pragma unroll
    for (int off = 1; off < 256; off <<= 1) {
        const int u = (t >= off) ? buf[t - off] : 0;
        __syncthreads();
        buf[t] += u;
        __syncthreads();
    }
    if (i < n) tmp[i] = buf[t];
    if (t == 255) blocksum[blockIdx.x] = buf[255];
}

// single-block scan of <=256 block sums -> exclusive offsets
__global__ __launch_bounds__(256) void scan2_kernel(int* __restrict__ blocksum, int nb) {
    __shared__ int buf[256];
    const int t = threadIdx.x;
    const int v = (t < nb) ? blocksum[t] : 0;
    buf[t] = v;
    __syncthreads();
#pragma unroll
    for (int off = 1; off < 256; off <<= 1) {
        const int u = (t >= off) ? buf[t - off] : 0;
        __syncthreads();
        buf[t] += u;
        __syncthreads();
    }
    if (t < nb) blocksum[t] = buf[t] - v;   // exclusive
}

__global__ __launch_bounds__(256) void scan3_kernel(const int* __restrict__ tmp,
                                                    const int* __restrict__ blocksum,
                                                    int* __restrict__ rowstart, int n) {
    const int i = blockIdx.x * 256 + threadIdx.x;
    if (i < n) rowstart[i + 1] = tmp[i] + blocksum[blockIdx.x];
    if (i == 0) rowstart[0] = 0;
}

__global__ __launch_bounds__(256) void scatter_kernel(const int* __restrict__ row,
                                                      const int* __restrict__ col,
                                                      const int* __restrict__ rowstart,
                                                      int* __restrict__ cursor,
                                                      int* __restrict__ sorted_col, int e) {
    const int i = blockIdx.x * 256 + threadIdx.x;
    if (i >= e) return;
    const int r = row[i];
    const int pos = atomicAdd(&cursor[r], 1);
    sorted_col[rowstart[r] + pos] = col[i];
}

// ---------------------------------------------------------------------------
// Aggregation + elu + log_softmax. One wave per row; lane holds 4 features.
// h gathered as bf16 (8B/lane), accumulated fp32. Edge loop unrolled x2.
// ---------------------------------------------------------------------------
__global__ __launch_bounds__(256) void aggregate_kernel(const unsigned short* __restrict__ hb,
                                                        const float* __restrict__ s_row,
                                                        const float* __restrict__ s_col,
                                                        const int* __restrict__ rowstart,
                                                        const int* __restrict__ sorted_col,
                                                        float* __restrict__ out, int n) {
    const int wave = (int)((blockIdx.x * (size_t)blockDim.x + threadIdx.x) >> 6);
    const int lane = threadIdx.x & 63;
    if (wave >= n) return;
    const int r = wave;
    const int jb = rowstart[r];
    const int je = rowstart[r + 1];
    const float sr = s_row[r];
    const int fo = lane << 2;

    float4 acc = make_float4(0.f, 0.f, 0.f, 0.f);
    float rowsum = 0.f;

    int j = jb;
    for (; j + 1 < je; j += 2) {
        const int c0 = sorted_col[j];
        const int c1 = sorted_col[j + 1];
        const ushort4 hv0 = *(const ushort4*)&hb[(size_t)c0 * NCLASS + fo];
        const ushort4 hv1 = *(const ushort4*)&hb[(size_t)c1 * NCLASS + fo];
        const float l0 = sr + s_col[c0];
        const float l1 = sr + s_col[c1];
        const float r0 = l0 > 0.f ? l0 : NEG_SLOPE * l0;
        const float r1 = l1 > 0.f ? l1 : NEG_SLOPE * l1;
        const float e0 = __expf(-r0);
        const float e1 = __expf(-r1);
        rowsum += e0 + e1;
        acc.x += e0 * bf2f(hv0.x) + e1 * bf2f(hv1.x);
        acc.y += e0 * bf2f(hv0.y) + e1 * bf2f(hv1.y);
        acc.z += e0 * bf2f(hv0.z) + e1 * bf2f(hv1.z);
        acc.w += e0 * bf2f(hv0.w) + e1 * bf2f(hv1.w);
    }
    if (j < je) {
        const int c = sorted_col[j];
        const ushort4 hv = *(const ushort4*)&hb[(size_t)c * NCLASS + fo];
        const float l0 = sr + s_col[c];
        const float r0 = l0 > 0.f ? l0 : NEG_SLOPE * l0;
        const float e = __expf(-r0);
        rowsum += e;
        acc.x += e * bf2f(hv.x);
        acc.y += e * bf2f(hv.y);
        acc.z += e * bf2f(hv.z);
        acc.w += e * bf2f(hv.w);
    }

    const float inv = 1.f / rowsum;
    float v[4] = {acc.x * inv, acc.y * inv, acc.z * inv, acc.w * inv};
#pragma unroll
    for (int i = 0; i < 4; ++i)
        v[i] = v[i] > 0.f ? v[i] : __expf(v[i]) - 1.f;

    float m = fmaxf(fmaxf(v[0], v[1]), fmaxf(v[2], v[3]));
#pragma unroll
    for (int off = 32; off > 0; off >>= 1) m = fmaxf(m, __shfl_xor(m, off));
    float s = 0.f;
#pragma unroll
    for (int i = 0; i < 4; ++i) s += __expf(v[i] - m);
#pragma unroll
    for (int off = 32; off > 0; off >>= 1) s += __shfl_xor(s, off);
    const float lse = m + __logf(s);

    float4 o = make_float4(v[0] - lse, v[1] - lse, v[2] - lse, v[3] - lse);
    *(float4*)&out[(size_t)r * NCLASS + fo] = o;
}

// ---------------------------------------------------------------------------
extern "C" void kernel_launch(void* const* d_in, const int* in_sizes, int n_in,
                              void* d_out, int out_size, void* d_ws, size_t ws_size,
                              hipStream_t stream) {
    const float* x  = (const float*)d_in[0];   // [N, 512]
    const float* W  = (const float*)d_in[1];   // [512, 256]
    const float* a  = (const float*)d_in[2];   // [512]
    const int* edge = (const int*)d_in[3];     // [2, E]
    float* out = (float*)d_out;

    const int M = in_sizes[0] / NFEAT;         // 50000
    const int E = in_sizes[3] / 2;             // 850000
    const int* row = edge;
    const int* col = edge + E;

    char* ws = (char*)d_ws;
    size_t off = 0;
    auto carve = [&](size_t bytes) -> char* {
        char* p = ws + off;
        off = (off + bytes + 255) & ~(size_t)255;
        return p;
    };
    unsigned short* xb = (unsigned short*)carve((size_t)MPAD * NFEAT * sizeof(short)); // 51.3MB
    unsigned short* Wt = (unsigned short*)carve((size_t)NCLASS * NFEAT * sizeof(short));
    unsigned short* hb = (unsigned short*)carve((size_t)M * NCLASS * sizeof(short));   // 25.6MB
    float* s_row    = (float*)carve((size_t)M * sizeof(float));
    float* s_col    = (float*)carve((size_t)M * sizeof(float));
    int*   deg      = (int*)carve((size_t)2 * M * sizeof(int));  // deg + cursor contiguous
    int*   cursor   = deg + M;
    int*   rowstart = (int*)carve((size_t)(M + 1) * sizeof(int));
    int*   tmp_scan = (int*)carve((size_t)M * sizeof(int));
    int*   blocksum = (int*)carve((size_t)256 * sizeof(int));
    int*   sorted_col = (int*)carve((size_t)E * sizeof(int));

    hipMemsetAsync(deg, 0, (size_t)2 * M * sizeof(int), stream);

    const int n8 = M * NFEAT / 8;
    cvt_x_kernel<<<(n8 + 255) / 256, 256, 0, stream>>>(x, xb, n8);
    cvt_wt_kernel<<<(NCLASS * NFEAT) / 256, 256, 0, stream>>>(W, Wt);

    dim3 ggrid(MPAD / 128, NCLASS / 128);
    gemm_mfma_kernel<<<ggrid, 256, 0, stream>>>(xb, Wt, hb, M);

    compute_s_kernel<<<(M + 3) / 4, 256, 0, stream>>>(hb, a, s_row, s_col, M);

    const int nb1 = (M + 255) / 256;   // 196
    hist_kernel<<<(E + 255) / 256, 256, 0, stream>>>(row, deg, E);
    scan1_kernel<<<nb1, 256, 0, stream>>>(deg, tmp_scan, blocksum, M);
    scan2_kernel<<<1, 256, 0, stream>>>(blocksum, nb1);
    scan3_kernel<<<nb1, 256, 0, stream>>>(tmp_scan, blocksum, rowstart, M);
    scatter_kernel<<<(E + 255) / 256, 256, 0, stream>>>(row, col, rowstart, cursor, sorted_col, E);

    aggregate_kernel<<<(M + 3) / 4, 256, 0, stream>>>(hb, s_row, s_col, rowstart, sorted_col, out, M);
}

// Round 3
// 361.001 us; speedup vs baseline: 1.7032x; 1.0326x over previous
//
#include <hip/hip_runtime.h>
#include <math.h>

#define NNODES   50000
#define NFEAT    512
#define NCLASS   256
#define NEG_SLOPE 0.2f
#define MPAD     50048   // 391 * 128

typedef __attribute__((ext_vector_type(8))) short short8;
typedef __attribute__((ext_vector_type(4))) float floatx4;

__device__ __forceinline__ unsigned short f2bf(float f) {
    unsigned u = __builtin_bit_cast(unsigned, f);
    u += 0x7fffu + ((u >> 16) & 1u);          // RNE
    return (unsigned short)(u >> 16);
}
__device__ __forceinline__ float bf2f(unsigned short s) {
    unsigned u = ((unsigned)s) << 16;
    return __builtin_bit_cast(float, u);
}

// ---------------------------------------------------------------------------
// Fused conversion: x -> xb (8 floats/thread), W -> Wt transposed (1/thread)
// ---------------------------------------------------------------------------
__global__ __launch_bounds__(256) void cvt_kernel(const float* __restrict__ x,
                                                  unsigned short* __restrict__ xb,
                                                  const float* __restrict__ W,
                                                  unsigned short* __restrict__ Wt, int n8) {
    const int i = blockIdx.x * 256 + threadIdx.x;
    if (i < n8) {
        const float4* p = (const float4*)(x + (size_t)i * 8);
        const float4 v0 = p[0];
        const float4 v1 = p[1];
        uint4 o;
        o.x = (unsigned)f2bf(v0.x) | ((unsigned)f2bf(v0.y) << 16);
        o.y = (unsigned)f2bf(v0.z) | ((unsigned)f2bf(v0.w) << 16);
        o.z = (unsigned)f2bf(v1.x) | ((unsigned)f2bf(v1.y) << 16);
        o.w = (unsigned)f2bf(v1.z) | ((unsigned)f2bf(v1.w) << 16);
        *(uint4*)(xb + (size_t)i * 8) = o;
    } else {
        const int t = i - n8;
        if (t < NCLASS * NFEAT) {
            const int n = t >> 9;
            const int k = t & 511;
            Wt[t] = f2bf(W[(size_t)k * NCLASS + n]);
        }
    }
}

// ---------------------------------------------------------------------------
// MFMA GEMM: hb = bf16( xb[MPAD,512] @ Wt^T )  -> [M,256] bf16
// 128x128 block tile, 4 waves (2x2 of 64x64), BK=32, global_load_lds(16B).
// Epilogue staged through LDS for coalesced uint2 stores.
// ---------------------------------------------------------------------------
__global__ __launch_bounds__(256) void gemm_mfma_kernel(const unsigned short* __restrict__ xb,
                                                        const unsigned short* __restrict__ Wt,
                                                        unsigned short* __restrict__ hb, int M) {
    __shared__ short As[128 * 32];   // [row][k], 64B rows
    __shared__ short Bs[128 * 32];   // [n][k],   64B rows
    __shared__ short Cs[64 * 132];   // epilogue staging, +4 pad (2-way-free banks)

    const int tid  = threadIdx.x;
    const int w    = tid >> 6;
    const int lane = tid & 63;
    const int rowbase = blockIdx.x * 128;
    const int nbase   = blockIdx.y * 128;

    const int wm = w & 1;   // wave's 64-row half
    const int wn = w >> 1;  // wave's 64-col half

    // staging: wave w covers segs {2w, 2w+1}; each seg = 16 rows x 32 k (1024B)
    const int srow = (lane >> 2);        // 0..15 within seg
    const int skq  = (lane & 3) << 3;    // k offset 0,8,16,24

    // fragment LDS offsets (in shorts)
    const int fm = lane & 15;
    const int fq = lane >> 4;

    floatx4 acc[4][4];
#pragma unroll
    for (int i = 0; i < 4; ++i)
#pragma unroll
        for (int j = 0; j < 4; ++j)
            acc[i][j] = (floatx4){0.f, 0.f, 0.f, 0.f};

    for (int k0 = 0; k0 < NFEAT; k0 += 32) {
#pragma unroll
        for (int t = 0; t < 2; ++t) {
            const int seg = w * 2 + t;
            const int r = seg * 16 + srow;
            __builtin_amdgcn_global_load_lds(
                (const __attribute__((address_space(1))) void*)(xb + (size_t)(rowbase + r) * NFEAT + k0 + skq),
                (__attribute__((address_space(3))) void*)(As + seg * 512), 16, 0, 0);
            __builtin_amdgcn_global_load_lds(
                (const __attribute__((address_space(1))) void*)(Wt + (size_t)(nbase + r) * NFEAT + k0 + skq),
                (__attribute__((address_space(3))) void*)(Bs + seg * 512), 16, 0, 0);
        }
        __syncthreads();

        short8 af[4], bfr[4];
#pragma unroll
        for (int mt = 0; mt < 4; ++mt)
            af[mt] = *(const short8*)&As[(wm * 64 + mt * 16 + fm) * 32 + fq * 8];
#pragma unroll
        for (int nt = 0; nt < 4; ++nt)
            bfr[nt] = *(const short8*)&Bs[(wn * 64 + nt * 16 + fm) * 32 + fq * 8];

#pragma unroll
        for (int mt = 0; mt < 4; ++mt)
#pragma unroll
            for (int nt = 0; nt < 4; ++nt)
                acc[mt][nt] = __builtin_amdgcn_mfma_f32_16x16x32_bf16(af[mt], bfr[nt], acc[mt][nt], 0, 0, 0);

        __syncthreads();
    }

    // Epilogue: two passes over row-halves; stage 64x128 bf16 in LDS, store coalesced.
    // C/D layout: col = lane&15, row = (lane>>4)*4 + r
    for (int p = 0; p < 2; ++p) {
        if (p) __syncthreads();
        if (wm == p) {
#pragma unroll
            for (int mt = 0; mt < 4; ++mt)
#pragma unroll
                for (int nt = 0; nt < 4; ++nt)
#pragma unroll
                    for (int r = 0; r < 4; ++r)
                        Cs[(mt * 16 + fq * 4 + r) * 132 + wn * 64 + nt * 16 + fm] =
                            (short)f2bf(acc[mt][nt][r]);
        }
        __syncthreads();
#pragma unroll
        for (int k = 0; k < 8; ++k) {
            const int idx = tid + k * 256;     // 0..2047 -> 64 rows x 32 chunks(4 shorts)
            const int lrow = idx >> 5;
            const int c4 = (idx & 31) << 2;
            const int grow = rowbase + p * 64 + lrow;
            if (grow < M) {
                const uint2 v = *(const uint2*)&Cs[lrow * 132 + c4];
                *(uint2*)&hb[(size_t)grow * NCLASS + nbase + c4] = v;
            }
        }
    }
}

// ---------------------------------------------------------------------------
// s_row[i] = h[i,:].a[0:256], s_col[i] = h[i,:].a[256:512]; one wave per row
// ---------------------------------------------------------------------------
__global__ __launch_bounds__(256) void compute_s_kernel(const unsigned short* __restrict__ hb,
                                                        const float* __restrict__ a,
                                                        float* __restrict__ s_row,
                                                        float* __restrict__ s_col, int n) {
    const int wave = (int)((blockIdx.x * (size_t)blockDim.x + threadIdx.x) >> 6);
    const int lane = threadIdx.x & 63;
    if (wave >= n) return;
    const ushort4 hv = *(const ushort4*)&hb[(size_t)wave * NCLASS + (lane << 2)];
    const float4 a1 = *(const float4*)&a[lane << 2];
    const float4 a2 = *(const float4*)&a[NCLASS + (lane << 2)];
    const float h0 = bf2f(hv.x), h1 = bf2f(hv.y), h2 = bf2f(hv.z), h3 = bf2f(hv.w);
    float d1 = h0 * a1.x + h1 * a1.y + h2 * a1.z + h3 * a1.w;
    float d2 = h0 * a2.x + h1 * a2.y + h2 * a2.z + h3 * a2.w;
#pragma unroll
    for (int off = 32; off > 0; off >>= 1) {
        d1 += __shfl_xor(d1, off);
        d2 += __shfl_xor(d2, off);
    }
    if (lane == 0) {
        s_row[wave] = d1;
        s_col[wave] = d2;
    }
}

// ---------------------------------------------------------------------------
// CSR build: histogram -> scan (two-level, scan2 folded into scan3) -> scatter
// ---------------------------------------------------------------------------
__global__ __launch_bounds__(256) void hist_kernel(const int* __restrict__ row,
                                                   int* __restrict__ deg, int e) {
    const int i = blockIdx.x * 256 + threadIdx.x;
    if (i < e) atomicAdd(&deg[row[i]], 1);
}

__global__ __launch_bounds__(256) void scan1_kernel(const int* __restrict__ deg,
                                                    int* __restrict__ tmp,
                                                    int* __restrict__ blocksum, int n) {
    __shared__ int buf[256];
    const int i = blockIdx.x * 256 + threadIdx.x;
    const int t = threadIdx.x;
    buf[t] = (i < n) ? deg[i] : 0;
    __syncthreads();
#pragma unroll
    for (int off = 1; off < 256; off <<= 1) {
        const int u = (t >= off) ? buf[t - off] : 0;
        __syncthreads();
        buf[t] += u;
        __syncthreads();
    }
    if (i < n) tmp[i] = buf[t];
    if (t == 255) blocksum[blockIdx.x] = buf[255];
}

// each block redundantly scans blocksums in LDS, applies its exclusive offset
__global__ __launch_bounds__(256) void scan3_kernel(const int* __restrict__ tmp,
                                                    const int* __restrict__ blocksum,
                                                    int* __restrict__ rowstart, int n, int nb) {
    __shared__ int buf[256];
    const int t = threadIdx.x;
    buf[t] = (t < nb) ? blocksum[t] : 0;
    __syncthreads();
#pragma unroll
    for (int off = 1; off < 256; off <<= 1) {
        const int u = (t >= off) ? buf[t - off] : 0;
        __syncthreads();
        buf[t] += u;
        __syncthreads();
    }
    const int boff = (blockIdx.x == 0) ? 0 : buf[blockIdx.x - 1];
    const int i = blockIdx.x * 256 + t;
    if (i < n) rowstart[i + 1] = tmp[i] + boff;
    if (i == 0) rowstart[0] = 0;
}

// scatter with fused attention-weight computation: store {col, e} per edge
__global__ __launch_bounds__(256) void scatter_kernel(const int* __restrict__ row,
                                                      const int* __restrict__ col,
                                                      const float* __restrict__ s_row,
                                                      const float* __restrict__ s_col,
                                                      const int* __restrict__ rowstart,
                                                      int* __restrict__ cursor,
                                                      int2* __restrict__ sorted_ce, int e) {
    const int i = blockIdx.x * 256 + threadIdx.x;
    if (i >= e) return;
    const int r = row[i];
    const int c = col[i];
    const float logit = s_row[r] + s_col[c];
    const float lr = logit > 0.f ? logit : NEG_SLOPE * logit;
    const float ew = __expf(-lr);
    const int pos = atomicAdd(&cursor[r], 1);
    int2 v;
    v.x = c;
    v.y = __builtin_bit_cast(int, ew);
    sorted_ce[rowstart[r] + pos] = v;
}

// ---------------------------------------------------------------------------
// Aggregation + elu + log_softmax. One wave per row; lane holds 4 features.
// Edge records are {col, e}; unrolled x4 for gather MLP.
// ---------------------------------------------------------------------------
__global__ __launch_bounds__(256) void aggregate_kernel(const unsigned short* __restrict__ hb,
                                                        const int2* __restrict__ sorted_ce,
                                                        const int* __restrict__ rowstart,
                                                        float* __restrict__ out, int n) {
    const int wave = (int)((blockIdx.x * (size_t)blockDim.x + threadIdx.x) >> 6);
    const int lane = threadIdx.x & 63;
    if (wave >= n) return;
    const int r = wave;
    const int jb = rowstart[r];
    const int je = rowstart[r + 1];
    const int fo = lane << 2;

    float4 acc = make_float4(0.f, 0.f, 0.f, 0.f);
    float rowsum = 0.f;

    int j = jb;
    for (; j + 3 < je; j += 4) {
        const int2 v0 = sorted_ce[j];
        const int2 v1 = sorted_ce[j + 1];
        const int2 v2 = sorted_ce[j + 2];
        const int2 v3 = sorted_ce[j + 3];
        const ushort4 h0 = *(const ushort4*)&hb[(size_t)v0.x * NCLASS + fo];
        const ushort4 h1 = *(const ushort4*)&hb[(size_t)v1.x * NCLASS + fo];
        const ushort4 h2 = *(const ushort4*)&hb[(size_t)v2.x * NCLASS + fo];
        const ushort4 h3 = *(const ushort4*)&hb[(size_t)v3.x * NCLASS + fo];
        const float e0 = __builtin_bit_cast(float, v0.y);
        const float e1 = __builtin_bit_cast(float, v1.y);
        const float e2 = __builtin_bit_cast(float, v2.y);
        const float e3 = __builtin_bit_cast(float, v3.y);
        rowsum += (e0 + e1) + (e2 + e3);
        acc.x += e0 * bf2f(h0.x) + e1 * bf2f(h1.x) + e2 * bf2f(h2.x) + e3 * bf2f(h3.x);
        acc.y += e0 * bf2f(h0.y) + e1 * bf2f(h1.y) + e2 * bf2f(h2.y) + e3 * bf2f(h3.y);
        acc.z += e0 * bf2f(h0.z) + e1 * bf2f(h1.z) + e2 * bf2f(h2.z) + e3 * bf2f(h3.z);
        acc.w += e0 * bf2f(h0.w) + e1 * bf2f(h1.w) + e2 * bf2f(h2.w) + e3 * bf2f(h3.w);
    }
    for (; j < je; ++j) {
        const int2 v = sorted_ce[j];
        const ushort4 hv = *(const ushort4*)&hb[(size_t)v.x * NCLASS + fo];
        const float e = __builtin_bit_cast(float, v.y);
        rowsum += e;
        acc.x += e * bf2f(hv.x);
        acc.y += e * bf2f(hv.y);
        acc.z += e * bf2f(hv.z);
        acc.w += e * bf2f(hv.w);
    }

    const float inv = 1.f / rowsum;
    float v[4] = {acc.x * inv, acc.y * inv, acc.z * inv, acc.w * inv};
#pragma unroll
    for (int i = 0; i < 4; ++i)
        v[i] = v[i] > 0.f ? v[i] : __expf(v[i]) - 1.f;

    float m = fmaxf(fmaxf(v[0], v[1]), fmaxf(v[2], v[3]));
#pragma unroll
    for (int off = 32; off > 0; off >>= 1) m = fmaxf(m, __shfl_xor(m, off));
    float s = 0.f;
#pragma unroll
    for (int i = 0; i < 4; ++i) s += __expf(v[i] - m);
#pragma unroll
    for (int off = 32; off > 0; off >>= 1) s += __shfl_xor(s, off);
    const float lse = m + __logf(s);

    float4 o = make_float4(v[0] - lse, v[1] - lse, v[2] - lse, v[3] - lse);
    *(float4*)&out[(size_t)r * NCLASS + fo] = o;
}

// ---------------------------------------------------------------------------
extern "C" void kernel_launch(void* const* d_in, const int* in_sizes, int n_in,
                              void* d_out, int out_size, void* d_ws, size_t ws_size,
                              hipStream_t stream) {
    const float* x  = (const float*)d_in[0];   // [N, 512]
    const float* W  = (const float*)d_in[1];   // [512, 256]
    const float* a  = (const float*)d_in[2];   // [512]
    const int* edge = (const int*)d_in[3];     // [2, E]
    float* out = (float*)d_out;

    const int M = in_sizes[0] / NFEAT;         // 50000
    const int E = in_sizes[3] / 2;             // 850000
    const int* row = edge;
    const int* col = edge + E;

    char* ws = (char*)d_ws;
    size_t off = 0;
    auto carve = [&](size_t bytes) -> char* {
        char* p = ws + off;
        off = (off + bytes + 255) & ~(size_t)255;
        return p;
    };
    unsigned short* xb = (unsigned short*)carve((size_t)MPAD * NFEAT * sizeof(short)); // 51.3MB
    unsigned short* Wt = (unsigned short*)carve((size_t)NCLASS * NFEAT * sizeof(short));
    unsigned short* hb = (unsigned short*)carve((size_t)M * NCLASS * sizeof(short));   // 25.6MB
    float* s_row    = (float*)carve((size_t)M * sizeof(float));
    float* s_col    = (float*)carve((size_t)M * sizeof(float));
    int*   deg      = (int*)carve((size_t)2 * M * sizeof(int));  // deg + cursor contiguous
    int*   cursor   = deg + M;
    int*   rowstart = (int*)carve((size_t)(M + 1) * sizeof(int));
    int*   tmp_scan = (int*)carve((size_t)M * sizeof(int));
    int*   blocksum = (int*)carve((size_t)256 * sizeof(int));
    // sorted {col,e} records alias the xb buffer: xb is dead after gemm,
    // and scatter runs strictly after gemm on the same stream. 850K*8B = 6.8MB.
    int2*  sorted_ce = (int2*)xb;

    hipMemsetAsync(deg, 0, (size_t)2 * M * sizeof(int), stream);

    const int n8 = M * NFEAT / 8;
    const int cvt_total = n8 + NCLASS * NFEAT;
    cvt_kernel<<<(cvt_total + 255) / 256, 256, 0, stream>>>(x, xb, W, Wt, n8);

    dim3 ggrid(MPAD / 128, NCLASS / 128);
    gemm_mfma_kernel<<<ggrid, 256, 0, stream>>>(xb, Wt, hb, M);

    compute_s_kernel<<<(M + 3) / 4, 256, 0, stream>>>(hb, a, s_row, s_col, M);

    const int nb1 = (M + 255) / 256;   // 196
    hist_kernel<<<(E + 255) / 256, 256, 0, stream>>>(row, deg, E);
    scan1_kernel<<<nb1, 256, 0, stream>>>(deg, tmp_scan, blocksum, M);
    scan3_kernel<<<nb1, 256, 0, stream>>>(tmp_scan, blocksum, rowstart, M, nb1);
    scatter_kernel<<<(E + 255) / 256, 256, 0, stream>>>(row, col, s_row, s_col,
                                                        rowstart, cursor, sorted_ce, E);

    aggregate_kernel<<<(M + 3) / 4, 256, 0, stream>>>(hb, sorted_ce, rowstart, out, M);
}